// Round 4
// baseline (3049.350 us; speedup 1.0000x reference)
//
#include <hip/hip_runtime.h>

typedef unsigned short u16;
typedef unsigned int u32;

#define TT 256
#define DD 512
#define HH 8
#define DHH 64
#define NC 2560   // 5*H*DH

// ---------------- Kernel 1: proj = x @ W_kkqvv + b, scattered to [v][h][t][dh]
__global__ __launch_bounds__(256) void proj_kernel(
    const float* __restrict__ x, const float* __restrict__ W,
    const float* __restrict__ bias, float* __restrict__ five) {
    __shared__ float xs[16 * 512];
    const int r0 = blockIdx.x * 16;
    const int c0 = blockIdx.y * 256;
    const int tid = threadIdx.x;
    const float4* xp = (const float4*)(x + r0 * DD);
    float4* xs4 = (float4*)xs;
#pragma unroll
    for (int k = 0; k < 8; ++k) xs4[k * 256 + tid] = xp[k * 256 + tid];
    __syncthreads();
    const int col = c0 + tid;
    float acc[16];
#pragma unroll
    for (int r = 0; r < 16; ++r) acc[r] = 0.f;
    for (int d = 0; d < DD; ++d) {
        float w = W[d * NC + col];
#pragma unroll
        for (int r = 0; r < 16; ++r) acc[r] += xs[r * 512 + d] * w;
    }
    const float b = bias[col];
    const int v = col >> 9;
    const int h = (col >> 6) & 7;
    const int e = col & 63;
    float* outp = five + (((v * HH + h) * TT + r0) * DHH + e);
#pragma unroll
    for (int r = 0; r < 16; ++r) outp[r * DHH] = acc[r] + b;
}

// ---------------- Kernel 2: straightforward fused trilinear attention
// grid (64, 8): block = (head n, t0 = 4*blockIdx.x), 256 threads, thread = q.
__global__ void main_kernel(
    const float* __restrict__ five, const float* __restrict__ W_Kq,
    const float* __restrict__ W_Vq, float* __restrict__ Zb, float* __restrict__ Lb) {
    __shared__ float Ms[64 * 64];   // M_t[k][i] = sum_j k2[t,j] W_Kq[n,k,j,i]
    __shared__ float Us[64 * 64];   // U_t[a][e] = sum_c v2[t,c] W_Vq[n,a,c,e]
    __shared__ float k2s[64];
    __shared__ float v2s[64];
    const int tid = threadIdx.x;
    const int n  = blockIdx.y;
    const int t0 = blockIdx.x * 4;

    const float* k1p = five + (0 * HH + n) * TT * DHH;
    const float* k2p = five + (1 * HH + n) * TT * DHH;
    const float* qp  = five + (2 * HH + n) * TT * DHH;
    const float* v1p = five + (3 * HH + n) * TT * DHH;
    const float* v2p = five + (4 * HH + n) * TT * DHH;

    const int q = tid;
    float Zx[64];
#pragma unroll
    for (int e = 0; e < 64; ++e) Zx[e] = 0.f;
    float Lx = 0.f;

    // builder role for this thread: row kk, columns i0..i0+15
    const int kk = tid >> 2;
    const int i0 = (tid & 3) * 16;
    const float* wK = W_Kq + ((n * 64 + kk) * 64) * 64 + i0;
    const float* wV = W_Vq + ((n * 64 + kk) * 64) * 64 + i0;

    for (int tt = 0; tt < 4; ++tt) {
        const int t = t0 + tt;
        __syncthreads();   // previous iteration's readers of Ms/Us are done
        if (tid < 64)       k2s[tid]      = k2p[t * DHH + tid];
        else if (tid < 128) v2s[tid - 64] = v2p[t * DHH + (tid - 64)];
        __syncthreads();

        // build M_t and U_t (fp32, no shuffles, no packing)
        {
            float mA[16], uA[16];
#pragma unroll
            for (int ii = 0; ii < 16; ++ii) { mA[ii] = 0.f; uA[ii] = 0.f; }
            for (int j = 0; j < 64; ++j) {
                const float cK = k2s[j];
                const float cV = v2s[j];
                const float* wKj = wK + j * 64;
                const float* wVj = wV + j * 64;
#pragma unroll
                for (int ii = 0; ii < 16; ++ii) {
                    mA[ii] += cK * wKj[ii];
                    uA[ii] += cV * wVj[ii];
                }
            }
#pragma unroll
            for (int ii = 0; ii < 16; ++ii) {
                Ms[kk * 64 + i0 + ii] = mA[ii];
                Us[kk * 64 + i0 + ii] = uA[ii];
            }
        }
        __syncthreads();

        if (q >= t) {
            // qv = q[q, :]
            float qv[64];
#pragma unroll
            for (int i4 = 0; i4 < 16; ++i4)
                ((float4*)qv)[i4] = ((const float4*)(qp + q * DHH))[i4];

            // QM[k] = sum_i qv[i] * M_t[k][i]
            float QM[64];
#pragma unroll
            for (int k = 0; k < 64; ++k) {
                float s = 0.f;
#pragma unroll
                for (int i = 0; i < 64; ++i) s += qv[i] * Ms[k * 64 + i];
                QM[k] = s;
            }

            // p-loop: s = QM . k1[p,:]; w = exp(s/64); G += w * v1[p,:]
            float G[64];
#pragma unroll
            for (int a = 0; a < 64; ++a) G[a] = 0.f;
            for (int p = 0; p <= q; ++p) {
                const float* k1r = k1p + p * DHH;
                float s = 0.f;
#pragma unroll
                for (int k = 0; k < 64; ++k) s += QM[k] * k1r[k];
                float w = __expf(s * 0.015625f);
                Lx += w;
                const float* v1r = v1p + p * DHH;
#pragma unroll
                for (int a = 0; a < 64; ++a) G[a] += w * v1r[a];
            }

            // Zx[e] += sum_a G[a] * U_t[a][e]
#pragma unroll 4
            for (int a = 0; a < 64; ++a) {
                const float g = G[a];
#pragma unroll
                for (int e = 0; e < 64; ++e) Zx[e] += g * Us[a * 64 + e];
            }
        }
    }

    if (q >= t0) {
        float* zp = Zb + (n * TT + q) * DHH;
#pragma unroll
        for (int e = 0; e < 64; ++e) atomicAdd(&zp[e], Zx[e]);
        atomicAdd(&Lb[n * TT + q], Lx);
    }
}

// ---------------- Kernel 3: out = (Z/L reordered) @ W_out + b_out (fp32 out)
__global__ __launch_bounds__(256) void out_kernel(
    const float* __restrict__ Zb, const float* __restrict__ Lb,
    const float* __restrict__ W_out, const float* __restrict__ b_out,
    float* __restrict__ out) {
    __shared__ float zs[16 * 512];
    const int r0 = blockIdx.x * 16;
    const int c0 = blockIdx.y * 256;
    const int tid = threadIdx.x;
    for (int k = 0; k < 32; ++k) {
        int idx = k * 256 + tid;
        int row = idx >> 9, hd = idx & 511;
        int h = hd >> 6, e = hd & 63;
        zs[idx] = Zb[(h * TT + r0 + row) * DHH + e] / Lb[h * TT + r0 + row];
    }
    __syncthreads();
    const int col = c0 + tid;
    float acc[16];
#pragma unroll
    for (int r = 0; r < 16; ++r) acc[r] = 0.f;
    for (int kk = 0; kk < 512; ++kk) {
        float w = W_out[kk * DD + col];
#pragma unroll
        for (int r = 0; r < 16; ++r) acc[r] += zs[r * 512 + kk] * w;
    }
    const float b = b_out[col];
#pragma unroll
    for (int r = 0; r < 16; ++r) out[(r0 + r) * DD + col] = acc[r] + b;
}

extern "C" void kernel_launch(void* const* d_in, const int* in_sizes, int n_in,
                              void* d_out, int out_size, void* d_ws, size_t ws_size,
                              hipStream_t stream) {
    const float* x       = (const float*)d_in[0];
    const float* W_kkqvv = (const float*)d_in[1];
    const float* b_kkqvv = (const float*)d_in[2];
    const float* W_Kq    = (const float*)d_in[3];
    const float* W_Vq    = (const float*)d_in[4];
    const float* W_out   = (const float*)d_in[5];
    const float* b_out   = (const float*)d_in[6];

    float* five = (float*)d_ws;                 // 5*8*256*64 = 655360 floats
    float* Zb = five + 5 * HH * TT * DHH;       // 131072 floats
    float* Lb = Zb + HH * TT * DHH;             // 2048 floats

    hipMemsetAsync(Zb, 0, (HH * TT * DHH + HH * TT) * sizeof(float), stream);
    proj_kernel<<<dim3(16, 10), 256, 0, stream>>>(x, W_kkqvv, b_kkqvv, five);
    main_kernel<<<dim3(64, 8), 256, 0, stream>>>(five, W_Kq, W_Vq, Zb, Lb);
    out_kernel<<<dim3(16, 2), 256, 0, stream>>>(Zb, Lb, W_out, b_out, (float*)d_out);
}

// Round 5
// 636.562 us; speedup vs baseline: 4.7903x; 4.7903x over previous
//
#include <hip/hip_runtime.h>

typedef unsigned short u16;
typedef unsigned int u32;
typedef __attribute__((ext_vector_type(8))) short bf16x8;
typedef __attribute__((ext_vector_type(4))) float f32x4;
#define MFMA __builtin_amdgcn_mfma_f32_16x16x32_bf16

#define TT 256
#define DD 512
#define HH 8
#define DHH 64
#define NC 2560   // 5*H*DH

__device__ __forceinline__ u16 f2bf(float f) {
    u32 x; __builtin_memcpy(&x, &f, 4);
    u32 r = (x + 0x7FFFu + ((x >> 16) & 1u)) >> 16;
    return (u16)r;
}
__device__ __forceinline__ void unpack2(u32 u, float& lo, float& hi) {
    u32 l = u << 16, h = u & 0xFFFF0000u;
    __builtin_memcpy(&lo, &l, 4); __builtin_memcpy(&hi, &h, 4);
}
__device__ __forceinline__ float sum8(uint4 u) {
    float f[8];
    unpack2(u.x, f[0], f[1]); unpack2(u.y, f[2], f[3]);
    unpack2(u.z, f[4], f[5]); unpack2(u.w, f[6], f[7]);
    return ((f[0]+f[1])+(f[2]+f[3]))+((f[4]+f[5])+(f[6]+f[7]));
}

// ---------------- K1: proj = x @ W_kkqvv + b  -> bf16 five_bf [5][h][t][dh]
__global__ __launch_bounds__(256) void proj_kernel(
    const float* __restrict__ x, const float* __restrict__ W,
    const float* __restrict__ bias, u16* __restrict__ fiveb) {
    __shared__ float xs[16 * 512];
    const int r0 = blockIdx.x * 16;
    const int c0 = blockIdx.y * 256;
    const int tid = threadIdx.x;
    const float4* xp = (const float4*)(x + r0 * DD);
    float4* xs4 = (float4*)xs;
#pragma unroll
    for (int k = 0; k < 8; ++k) xs4[k * 256 + tid] = xp[k * 256 + tid];
    __syncthreads();
    const int col = c0 + tid;
    float acc[16];
#pragma unroll
    for (int r = 0; r < 16; ++r) acc[r] = 0.f;
    for (int d = 0; d < DD; ++d) {
        float w = W[d * NC + col];
#pragma unroll
        for (int r = 0; r < 16; ++r) acc[r] += xs[r * 512 + d] * w;
    }
    const float b = bias[col];
    const int v = col >> 9;
    const int h = (col >> 6) & 7;
    const int e = col & 63;
    u16* outp = fiveb + (((v * HH + h) * TT + r0) * DHH + e);
#pragma unroll
    for (int r = 0; r < 16; ++r) outp[r * DHH] = f2bf(acc[r] + b);
}

// ---------------- K2: transpose weights to K-contiguous bf16
// WKt[n][k][i][j] = W_Kq[n][k][j][i]   (f = k*64+i, last dim j)
// WVt[n][e][a][c] = W_Vq[n][a][c][e]   (f = e*64+a, last dim c)
__global__ __launch_bounds__(256) void transpose_w(
    const float* __restrict__ WK, const float* __restrict__ WV,
    u16* __restrict__ WKt, u16* __restrict__ WVt) {
    __shared__ float S[64 * 65];
    const int outer = blockIdx.x, n = blockIdx.y, which = blockIdx.z;
    const float* in = (which ? WV : WK) + ((size_t)(n * 64 + outer)) * 4096;
    u16* outbase = (which ? WVt : WKt) + (size_t)n * 262144;
    const int tid = threadIdx.x;
    {
        int X = tid >> 2, c0 = (tid & 3) * 16;
        const float4* s = (const float4*)(in + X * 64 + c0);
        float4 v0 = s[0], v1 = s[1], v2 = s[2], v3 = s[3];
        float* d = &S[X * 65 + c0];
        d[0]=v0.x; d[1]=v0.y; d[2]=v0.z; d[3]=v0.w;
        d[4]=v1.x; d[5]=v1.y; d[6]=v1.z; d[7]=v1.w;
        d[8]=v2.x; d[9]=v2.y; d[10]=v2.z; d[11]=v2.w;
        d[12]=v3.x; d[13]=v3.y; d[14]=v3.z; d[15]=v3.w;
    }
    __syncthreads();
    {
        int Y = tid >> 2, x0 = (tid & 3) * 16;
        __attribute__((aligned(16))) u16 tmp[16];
#pragma unroll
        for (int xx = 0; xx < 16; ++xx) tmp[xx] = f2bf(S[(x0 + xx) * 65 + Y]);
        size_t strideY = which ? 4096 : 64;
        size_t strideO = which ? 64 : 4096;
        u16* d = outbase + (size_t)Y * strideY + (size_t)outer * strideO + x0;
        *(uint4*)d = *(uint4*)tmp;
        *(uint4*)(d + 8) = *(uint4*)(tmp + 8);
    }
}

// ---------------- K3: M_all[n][t][f] = sum_j k2[t,j]*WKt[n][f][j]  (U analog)
__global__ __launch_bounds__(256, 1) void mu_gemm(
    const u16* __restrict__ fiveb, const u16* __restrict__ WKt,
    const u16* __restrict__ WVt, u16* __restrict__ M_all, u16* __restrict__ U_all) {
    __shared__ u16 Cst[256 * 64];  // 32KB
    const int f0 = blockIdx.x * 64, n = blockIdx.y, which = blockIdx.z;
    const u16* vec = fiveb + ((which ? 4 : 1) * HH + n) * TT * DHH;
    const u16* W = (which ? WVt : WKt) + (size_t)n * 262144;
    u16* out = (which ? U_all : M_all) + (size_t)n * 1048576;
    const int tid = threadIdx.x, w = tid >> 6, lane = tid & 63;
    const int quad = lane >> 4, l15 = lane & 15;

    bf16x8 bf[4][2];
#pragma unroll
    for (int nt = 0; nt < 4; ++nt) {
        bf[nt][0] = *(const bf16x8*)&W[(size_t)(f0 + nt * 16 + l15) * 64 + quad * 8];
        bf[nt][1] = *(const bf16x8*)&W[(size_t)(f0 + nt * 16 + l15) * 64 + 32 + quad * 8];
    }
    f32x4 acc[4][4];
#pragma unroll
    for (int mt = 0; mt < 4; ++mt) {
        int trow = w * 64 + mt * 16 + l15;
        bf16x8 a0 = *(const bf16x8*)&vec[trow * 64 + quad * 8];
        bf16x8 a1 = *(const bf16x8*)&vec[trow * 64 + 32 + quad * 8];
#pragma unroll
        for (int nt = 0; nt < 4; ++nt) {
            f32x4 c = {0.f, 0.f, 0.f, 0.f};
            c = MFMA(a0, bf[nt][0], c, 0, 0, 0);
            c = MFMA(a1, bf[nt][1], c, 0, 0, 0);
            acc[mt][nt] = c;
        }
    }
#pragma unroll
    for (int mt = 0; mt < 4; ++mt)
#pragma unroll
        for (int nt = 0; nt < 4; ++nt)
#pragma unroll
            for (int r = 0; r < 4; ++r)
                Cst[(w * 64 + mt * 16 + quad * 4 + r) * 64 + nt * 16 + l15] = f2bf(acc[mt][nt][r]);
    __syncthreads();
    const uint4* src = (const uint4*)&Cst[tid * 64];
    uint4* dst = (uint4*)(out + (size_t)tid * 4096 + f0);
#pragma unroll
    for (int i = 0; i < 8; ++i) dst[i] = src[i];
}

// ---------------- K4: fused trilinear attention, MFMA everywhere
// grid (10, 8): causal (q-tile, t-chunk) pairs x heads, 256 threads.
__global__ __launch_bounds__(256, 1) void main_kernel(
    const u16* __restrict__ fiveb, const u16* __restrict__ M_all,
    const u16* __restrict__ U_all, float* __restrict__ Zb, float* __restrict__ Lb) {
    extern __shared__ u16 sm[];
    u16* qA  = sm;             // 64x72
    u16* k1B = sm + 4608;      // 256x72
    u16* v1T = sm + 23040;     // 64x264
    u16* Mt  = sm + 39936;     // 2 x 64x72
    u16* Ut  = sm + 49152;     // 2 x 64x72
    u16* QMb = sm + 58368;     // 64x72
    u16* Pb  = sm + 62976;     // 64x72  (aliased as G buffer)

    const int tid = threadIdx.x;
    const int n = blockIdx.y;
    const int pi = blockIdx.x;
    int qt, tc;
    if (pi < 1)      { qt = 0; tc = pi; }
    else if (pi < 3) { qt = 1; tc = pi - 1; }
    else if (pi < 6) { qt = 2; tc = pi - 3; }
    else             { qt = 3; tc = pi - 6; }
    const int q0 = qt * 64, t_0 = tc * 64;
    const int nP = qt + 1;

    const u16* k1g = fiveb + (0 * HH + n) * TT * DHH;
    const u16* qg  = fiveb + (2 * HH + n) * TT * DHH;
    const u16* v1g = fiveb + (3 * HH + n) * TT * DHH;

    // stage qA
    {
        int row = tid >> 2, c0 = (tid & 3) * 16;
        const uint4* s = (const uint4*)(qg + (q0 + row) * 64 + c0);
        uint4 a = s[0], b = s[1];
        *(uint4*)&qA[row * 72 + c0] = a;
        *(uint4*)&qA[row * 72 + c0 + 8] = b;
    }
    // stage k1B rows [0, 64*nP)
    for (int ch = 0; ch < nP; ++ch) {
        int row = ch * 64 + (tid >> 2), c0 = (tid & 3) * 16;
        const uint4* s = (const uint4*)(k1g + row * 64 + c0);
        uint4 a = s[0], b = s[1];
        *(uint4*)&k1B[row * 72 + c0] = a;
        *(uint4*)&k1B[row * 72 + c0 + 8] = b;
    }
    // stage v1T (transposed)
    {
        int a = tid & 63;
        for (int p = tid >> 6; p < nP * 64; p += 4)
            v1T[a * 264 + p] = v1g[p * 64 + a];
    }
    // stage M/U for t_0 into buf 0
    {
        const uint4* ms = (const uint4*)(M_all + ((size_t)(n * 256 + t_0)) * 4096);
        const uint4* us = (const uint4*)(U_all + ((size_t)(n * 256 + t_0)) * 4096);
        uint4 m0 = ms[tid * 2], m1 = ms[tid * 2 + 1];
        uint4 u0 = us[tid * 2], u1 = us[tid * 2 + 1];
        int k = tid >> 2, c0 = (tid & 3) * 16;
        *(uint4*)&Mt[k * 72 + c0] = m0; *(uint4*)&Mt[k * 72 + c0 + 8] = m1;
        *(uint4*)&Ut[k * 72 + c0] = u0; *(uint4*)&Ut[k * 72 + c0 + 8] = u1;
    }
    __syncthreads();

    const int w = tid >> 6, lane = tid & 63, quad = lane >> 4, l15 = lane & 15;
    const int r0 = w * 16;

    f32x4 Zc[4];
#pragma unroll
    for (int nt = 0; nt < 4; ++nt) Zc[nt] = (f32x4){0.f, 0.f, 0.f, 0.f};
    float lsum = 0.f;

    for (int tt = 0; tt < 64; ++tt) {
        const int t = t_0 + tt;
        const int cur = tt & 1;
        uint4 m0, m1, u0, u1;
        const bool pref = (tt + 1 < 64);
        if (pref) {
            const uint4* ms = (const uint4*)(M_all + ((size_t)(n * 256 + t + 1)) * 4096);
            const uint4* us = (const uint4*)(U_all + ((size_t)(n * 256 + t + 1)) * 4096);
            m0 = ms[tid * 2]; m1 = ms[tid * 2 + 1];
            u0 = us[tid * 2]; u1 = us[tid * 2 + 1];
        }
        const u16* Mc = Mt + cur * 4608;
        const u16* Uc = Ut + cur * 4608;

        // QM[q,k] = sum_i qA[q,i] * M_t[k,i]
        {
            bf16x8 a0 = *(bf16x8*)&qA[(r0 + l15) * 72 + quad * 8];
            bf16x8 a1 = *(bf16x8*)&qA[(r0 + l15) * 72 + 32 + quad * 8];
#pragma unroll
            for (int nt = 0; nt < 4; ++nt) {
                bf16x8 b0 = *(bf16x8*)&Mc[(nt * 16 + l15) * 72 + quad * 8];
                bf16x8 b1 = *(bf16x8*)&Mc[(nt * 16 + l15) * 72 + 32 + quad * 8];
                f32x4 c = {0.f, 0.f, 0.f, 0.f};
                c = MFMA(a0, b0, c, 0, 0, 0);
                c = MFMA(a1, b1, c, 0, 0, 0);
#pragma unroll
                for (int r = 0; r < 4; ++r)
                    QMb[(r0 + quad * 4 + r) * 72 + nt * 16 + l15] = f2bf(c[r]);
            }
        }

        f32x4 Gc[4];
#pragma unroll
        for (int nt = 0; nt < 4; ++nt) Gc[nt] = (f32x4){0.f, 0.f, 0.f, 0.f};

        for (int pt = 0; pt < nP; ++pt) {
            bf16x8 qa0 = *(bf16x8*)&QMb[(r0 + l15) * 72 + quad * 8];
            bf16x8 qa1 = *(bf16x8*)&QMb[(r0 + l15) * 72 + 32 + quad * 8];
            // S + mask + exp -> Pb
#pragma unroll
            for (int nt = 0; nt < 4; ++nt) {
                bf16x8 b0 = *(bf16x8*)&k1B[(pt * 64 + nt * 16 + l15) * 72 + quad * 8];
                bf16x8 b1 = *(bf16x8*)&k1B[(pt * 64 + nt * 16 + l15) * 72 + 32 + quad * 8];
                f32x4 s = {0.f, 0.f, 0.f, 0.f};
                s = MFMA(qa0, b0, s, 0, 0, 0);
                s = MFMA(qa1, b1, s, 0, 0, 0);
                const int p = pt * 64 + nt * 16 + l15;
#pragma unroll
                for (int r = 0; r < 4; ++r) {
                    const int q = q0 + r0 + quad * 4 + r;
                    float wv = (p <= q && t <= q) ? __expf(s[r] * 0.015625f) : 0.f;
                    Pb[(r0 + quad * 4 + r) * 72 + nt * 16 + l15] = f2bf(wv);
                }
            }
            // L row-sums from Pb (wave-local strip)
            {
                const uint4* pr = (const uint4*)&Pb[(r0 + l15) * 72 + quad * 16];
                lsum += sum8(pr[0]) + sum8(pr[1]);
            }
            // G += P . v1tile
            bf16x8 pa0 = *(bf16x8*)&Pb[(r0 + l15) * 72 + quad * 8];
            bf16x8 pa1 = *(bf16x8*)&Pb[(r0 + l15) * 72 + 32 + quad * 8];
#pragma unroll
            for (int nt = 0; nt < 4; ++nt) {
                bf16x8 b0 = *(bf16x8*)&v1T[(nt * 16 + l15) * 264 + pt * 64 + quad * 8];
                bf16x8 b1 = *(bf16x8*)&v1T[(nt * 16 + l15) * 264 + pt * 64 + 32 + quad * 8];
                Gc[nt] = MFMA(pa0, b0, Gc[nt], 0, 0, 0);
                Gc[nt] = MFMA(pa1, b1, Gc[nt], 0, 0, 0);
            }
        }
        // Z += G . U_t   (G through LDS, aliasing Pb)
#pragma unroll
        for (int nt = 0; nt < 4; ++nt)
#pragma unroll
            for (int r = 0; r < 4; ++r)
                Pb[(r0 + quad * 4 + r) * 72 + nt * 16 + l15] = f2bf(Gc[nt][r]);
        bf16x8 ga0 = *(bf16x8*)&Pb[(r0 + l15) * 72 + quad * 8];
        bf16x8 ga1 = *(bf16x8*)&Pb[(r0 + l15) * 72 + 32 + quad * 8];
#pragma unroll
        for (int nt = 0; nt < 4; ++nt) {
            bf16x8 b0 = *(bf16x8*)&Uc[(nt * 16 + l15) * 72 + quad * 8];
            bf16x8 b1 = *(bf16x8*)&Uc[(nt * 16 + l15) * 72 + 32 + quad * 8];
            Zc[nt] = MFMA(ga0, b0, Zc[nt], 0, 0, 0);
            Zc[nt] = MFMA(ga1, b1, Zc[nt], 0, 0, 0);
        }
        __syncthreads();
        if (pref) {
            int k = tid >> 2, c0 = (tid & 3) * 16;
            int nxt = cur ^ 1;
            *(uint4*)&Mt[nxt * 4608 + k * 72 + c0] = m0;
            *(uint4*)&Mt[nxt * 4608 + k * 72 + c0 + 8] = m1;
            *(uint4*)&Ut[nxt * 4608 + k * 72 + c0] = u0;
            *(uint4*)&Ut[nxt * 4608 + k * 72 + c0 + 8] = u1;
        }
        __syncthreads();
    }

#pragma unroll
    for (int nt = 0; nt < 4; ++nt)
#pragma unroll
        for (int r = 0; r < 4; ++r) {
            const int q = q0 + r0 + quad * 4 + r;
            atomicAdd(Zb + ((size_t)n * 256 + q) * 64 + nt * 16 + l15, Zc[nt][r]);
        }
    lsum += __shfl_xor(lsum, 16);
    lsum += __shfl_xor(lsum, 32);
    if (quad == 0) atomicAdd(Lb + n * 256 + q0 + r0 + l15, lsum);
}

// ---------------- K5: out = (Z/L reordered) @ W_out + b_out (fp32 out)
__global__ __launch_bounds__(256) void out_kernel(
    const float* __restrict__ Zb, const float* __restrict__ Lb,
    const float* __restrict__ W_out, const float* __restrict__ b_out,
    float* __restrict__ out) {
    __shared__ float zs[16 * 512];
    const int r0 = blockIdx.x * 16;
    const int c0 = blockIdx.y * 256;
    const int tid = threadIdx.x;
    for (int k = 0; k < 32; ++k) {
        int idx = k * 256 + tid;
        int row = idx >> 9, hd = idx & 511;
        int h = hd >> 6, e = hd & 63;
        zs[idx] = Zb[(h * TT + r0 + row) * DHH + e] / Lb[h * TT + r0 + row];
    }
    __syncthreads();
    const int col = c0 + tid;
    float acc[16];
#pragma unroll
    for (int r = 0; r < 16; ++r) acc[r] = 0.f;
    for (int kk = 0; kk < 512; ++kk) {
        float w = W_out[kk * DD + col];
#pragma unroll
        for (int r = 0; r < 16; ++r) acc[r] += zs[r * 512 + kk] * w;
    }
    const float b = b_out[col];
#pragma unroll
    for (int r = 0; r < 16; ++r) out[(r0 + r) * DD + col] = acc[r] + b;
}

extern "C" void kernel_launch(void* const* d_in, const int* in_sizes, int n_in,
                              void* d_out, int out_size, void* d_ws, size_t ws_size,
                              hipStream_t stream) {
    const float* x       = (const float*)d_in[0];
    const float* W_kkqvv = (const float*)d_in[1];
    const float* b_kkqvv = (const float*)d_in[2];
    const float* W_Kq    = (const float*)d_in[3];
    const float* W_Vq    = (const float*)d_in[4];
    const float* W_out   = (const float*)d_in[5];
    const float* b_out   = (const float*)d_in[6];

    char* base = (char*)d_ws;
    u16*   fiveb = (u16*)base;                      // 655360 u16
    float* Zb    = (float*)(base + 1310720);        // 131072 f
    float* Lb    = (float*)(base + 1835008);        // 2048 f
    u16*   WKt   = (u16*)(base + 1843200);          // 2M u16
    u16*   WVt   = (u16*)(base + 6037504);          // 2M u16
    u16*   M_all = (u16*)(base + 10231808);         // 8M u16
    u16*   U_all = (u16*)(base + 27009024);         // 8M u16  (end ~43.8MB)

    hipFuncSetAttribute(reinterpret_cast<const void*>(main_kernel),
                        hipFuncAttributeMaxDynamicSharedMemorySize, 135168);

    hipMemsetAsync(Zb, 0, (HH * TT * DHH + HH * TT) * sizeof(float), stream);
    proj_kernel<<<dim3(16, 10), 256, 0, stream>>>(x, W_kkqvv, b_kkqvv, fiveb);
    transpose_w<<<dim3(64, 8, 2), 256, 0, stream>>>(W_Kq, W_Vq, WKt, WVt);
    mu_gemm<<<dim3(64, 8, 2), 256, 0, stream>>>(fiveb, WKt, WVt, M_all, U_all);
    main_kernel<<<dim3(10, 8), 256, 135168, stream>>>(fiveb, M_all, U_all, Zb, Lb);
    out_kernel<<<dim3(16, 2), 256, 0, stream>>>(Zb, Lb, W_out, b_out, (float*)d_out);
}

// Round 6
// 328.965 us; speedup vs baseline: 9.2695x; 1.9350x over previous
//
#include <hip/hip_runtime.h>

typedef unsigned short u16;
typedef unsigned int u32;
typedef __attribute__((ext_vector_type(8))) short bf16x8;
typedef __attribute__((ext_vector_type(4))) float f32x4;
#define MFMA __builtin_amdgcn_mfma_f32_16x16x32_bf16

#define TT 256
#define DD 512
#define HH 8
#define DHH 64
#define NC 2560   // 5*H*DH

__device__ __forceinline__ u16 f2bf(float f) {
    u32 x; __builtin_memcpy(&x, &f, 4);
    u32 r = (x + 0x7FFFu + ((x >> 16) & 1u)) >> 16;
    return (u16)r;
}
__device__ __forceinline__ void unpack2(u32 u, float& lo, float& hi) {
    u32 l = u << 16, h = u & 0xFFFF0000u;
    __builtin_memcpy(&lo, &l, 4); __builtin_memcpy(&hi, &h, 4);
}
__device__ __forceinline__ float sum8(uint4 u) {
    float f[8];
    unpack2(u.x, f[0], f[1]); unpack2(u.y, f[2], f[3]);
    unpack2(u.z, f[4], f[5]); unpack2(u.w, f[6], f[7]);
    return ((f[0]+f[1])+(f[2]+f[3]))+((f[4]+f[5])+(f[6]+f[7]));
}

// ---------------- K0: prep — Wt = bf16(W_kkqvv)^T, Wot = bf16(W_out)^T, xb = bf16(x)
__global__ __launch_bounds__(256) void prep_kernel(
    const float* __restrict__ W1, const float* __restrict__ Wo,
    const float* __restrict__ x,
    u16* __restrict__ Wt, u16* __restrict__ Wot, u16* __restrict__ xb) {
    __shared__ float S[64 * 65];
    const int bid = blockIdx.x, tid = threadIdx.x;
    if (bid < 384) {
        int tc, tr, Cw;
        const float* src; u16* dst;
        if (bid < 320) { tc = bid % 40; tr = bid / 40; src = W1; dst = Wt;  Cw = 2560; }
        else { int b2 = bid - 320; tc = b2 % 8; tr = b2 / 8; src = Wo; dst = Wot; Cw = 512; }
        {
            int X = tid >> 2, c0 = (tid & 3) * 16;
            const float4* s4 = (const float4*)(src + (size_t)(tr * 64 + X) * Cw + tc * 64 + c0);
            float4 v0 = s4[0], v1 = s4[1], v2 = s4[2], v3 = s4[3];
            float* d = &S[X * 65 + c0];
            d[0]=v0.x; d[1]=v0.y; d[2]=v0.z; d[3]=v0.w;
            d[4]=v1.x; d[5]=v1.y; d[6]=v1.z; d[7]=v1.w;
            d[8]=v2.x; d[9]=v2.y; d[10]=v2.z; d[11]=v2.w;
            d[12]=v3.x; d[13]=v3.y; d[14]=v3.z; d[15]=v3.w;
        }
        __syncthreads();
        {
            int Y = tid >> 2, x0 = (tid & 3) * 16;
            __attribute__((aligned(16))) u16 tmp[16];
#pragma unroll
            for (int xx = 0; xx < 16; ++xx) tmp[xx] = f2bf(S[(x0 + xx) * 65 + Y]);
            u16* o = dst + (size_t)(tc * 64 + Y) * 512 + tr * 64 + x0;
            *(uint4*)o = *(uint4*)tmp;
            *(uint4*)(o + 8) = *(uint4*)(tmp + 8);
        }
    } else {
        int b3 = bid - 384;            // 8 blocks cast x -> xb
        size_t base = (size_t)(b3 * 256 + tid) * 64;
        const float4* s = (const float4*)(x + base);
#pragma unroll
        for (int i = 0; i < 8; ++i) {
            float4 lo = s[2 * i], hi = s[2 * i + 1];
            __attribute__((aligned(16))) u16 t8[8];
            t8[0]=f2bf(lo.x); t8[1]=f2bf(lo.y); t8[2]=f2bf(lo.z); t8[3]=f2bf(lo.w);
            t8[4]=f2bf(hi.x); t8[5]=f2bf(hi.y); t8[6]=f2bf(hi.z); t8[7]=f2bf(hi.w);
            ((uint4*)(xb + base))[i] = *(uint4*)t8;
        }
    }
}

// ---------------- K1: proj MFMA: proj = xb @ Wt^T + b -> fiveb (v=3 goes to v1T transposed)
__global__ __launch_bounds__(256) void proj_mfma(
    const u16* __restrict__ xb, const u16* __restrict__ Wt,
    const float* __restrict__ bias, u16* __restrict__ fiveb, u16* __restrict__ v1T) {
    const int tid = threadIdx.x, w = tid >> 6, lane = tid & 63;
    const int quad = lane >> 4, l15 = lane & 15;
    const int m0 = blockIdx.x * 64 + w * 16;
    const int c0 = blockIdx.y * 64;
    f32x4 acc[4];
#pragma unroll
    for (int nt = 0; nt < 4; ++nt) acc[nt] = (f32x4){0.f, 0.f, 0.f, 0.f};
    for (int kc = 0; kc < 16; ++kc) {
        bf16x8 a = *(const bf16x8*)&xb[(size_t)(m0 + l15) * 512 + kc * 32 + quad * 8];
#pragma unroll
        for (int nt = 0; nt < 4; ++nt) {
            bf16x8 b = *(const bf16x8*)&Wt[(size_t)(c0 + nt * 16 + l15) * 512 + kc * 32 + quad * 8];
            acc[nt] = MFMA(a, b, acc[nt], 0, 0, 0);
        }
    }
#pragma unroll
    for (int nt = 0; nt < 4; ++nt) {
        const int col = c0 + nt * 16 + l15;
        const float b = bias[col];
        const int v = col >> 9, h = (col >> 6) & 7, e = col & 63;
#pragma unroll
        for (int r = 0; r < 4; ++r) {
            const int t = m0 + quad * 4 + r;
            u16 val = f2bf(acc[nt][r] + b);
            if (v == 3) v1T[(h * 64 + e) * 256 + t] = val;
            else        fiveb[((v * 8 + h) * 256 + t) * 64 + e] = val;
        }
    }
}

// ---------------- K2: transpose weights to K-contiguous bf16 (unchanged from r5)
__global__ __launch_bounds__(256) void transpose_w(
    const float* __restrict__ WK, const float* __restrict__ WV,
    u16* __restrict__ WKt, u16* __restrict__ WVt) {
    __shared__ float S[64 * 65];
    const int outer = blockIdx.x, n = blockIdx.y, which = blockIdx.z;
    const float* in = (which ? WV : WK) + ((size_t)(n * 64 + outer)) * 4096;
    u16* outbase = (which ? WVt : WKt) + (size_t)n * 262144;
    const int tid = threadIdx.x;
    {
        int X = tid >> 2, c0 = (tid & 3) * 16;
        const float4* s = (const float4*)(in + X * 64 + c0);
        float4 v0 = s[0], v1 = s[1], v2 = s[2], v3 = s[3];
        float* d = &S[X * 65 + c0];
        d[0]=v0.x; d[1]=v0.y; d[2]=v0.z; d[3]=v0.w;
        d[4]=v1.x; d[5]=v1.y; d[6]=v1.z; d[7]=v1.w;
        d[8]=v2.x; d[9]=v2.y; d[10]=v2.z; d[11]=v2.w;
        d[12]=v3.x; d[13]=v3.y; d[14]=v3.z; d[15]=v3.w;
    }
    __syncthreads();
    {
        int Y = tid >> 2, x0 = (tid & 3) * 16;
        __attribute__((aligned(16))) u16 tmp[16];
#pragma unroll
        for (int xx = 0; xx < 16; ++xx) tmp[xx] = f2bf(S[(x0 + xx) * 65 + Y]);
        size_t strideY = which ? 4096 : 64;
        size_t strideO = which ? 64 : 4096;
        u16* d = outbase + (size_t)Y * strideY + (size_t)outer * strideO + x0;
        *(uint4*)d = *(uint4*)tmp;
        *(uint4*)(d + 8) = *(uint4*)(tmp + 8);
    }
}

// ---------------- K3: M_all[n][t][f] = sum_j k2[t,j]*WKt[n][f][j]  (unchanged from r5)
__global__ __launch_bounds__(256, 1) void mu_gemm(
    const u16* __restrict__ fiveb, const u16* __restrict__ WKt,
    const u16* __restrict__ WVt, u16* __restrict__ M_all, u16* __restrict__ U_all) {
    __shared__ u16 Cst[256 * 64];
    const int f0 = blockIdx.x * 64, n = blockIdx.y, which = blockIdx.z;
    const u16* vec = fiveb + ((which ? 4 : 1) * HH + n) * TT * DHH;
    const u16* W = (which ? WVt : WKt) + (size_t)n * 262144;
    u16* out = (which ? U_all : M_all) + (size_t)n * 1048576;
    const int tid = threadIdx.x, w = tid >> 6, lane = tid & 63;
    const int quad = lane >> 4, l15 = lane & 15;

    bf16x8 bf[4][2];
#pragma unroll
    for (int nt = 0; nt < 4; ++nt) {
        bf[nt][0] = *(const bf16x8*)&W[(size_t)(f0 + nt * 16 + l15) * 64 + quad * 8];
        bf[nt][1] = *(const bf16x8*)&W[(size_t)(f0 + nt * 16 + l15) * 64 + 32 + quad * 8];
    }
    f32x4 acc[4][4];
#pragma unroll
    for (int mt = 0; mt < 4; ++mt) {
        int trow = w * 64 + mt * 16 + l15;
        bf16x8 a0 = *(const bf16x8*)&vec[trow * 64 + quad * 8];
        bf16x8 a1 = *(const bf16x8*)&vec[trow * 64 + 32 + quad * 8];
#pragma unroll
        for (int nt = 0; nt < 4; ++nt) {
            f32x4 c = {0.f, 0.f, 0.f, 0.f};
            c = MFMA(a0, bf[nt][0], c, 0, 0, 0);
            c = MFMA(a1, bf[nt][1], c, 0, 0, 0);
            acc[mt][nt] = c;
        }
    }
#pragma unroll
    for (int mt = 0; mt < 4; ++mt)
#pragma unroll
        for (int nt = 0; nt < 4; ++nt)
#pragma unroll
            for (int r = 0; r < 4; ++r)
                Cst[(w * 64 + mt * 16 + quad * 4 + r) * 64 + nt * 16 + l15] = f2bf(acc[mt][nt][r]);
    __syncthreads();
    const uint4* src = (const uint4*)&Cst[tid * 64];
    uint4* dst = (uint4*)(out + (size_t)tid * 4096 + f0);
#pragma unroll
    for (int i = 0; i < 8; ++i) dst[i] = src[i];
}

// ---------------- K4: fused trilinear attention — wave-local LDS only, no loop barriers
// grid (80, 8): pi -> (q-tile of 64, t-chunk of 8); 256 threads = 4 waves (wave = 16 q-rows).
__global__ __launch_bounds__(256, 4) void main_kernel(
    const u16* __restrict__ fiveb, const u16* __restrict__ v1T,
    const u16* __restrict__ M_all, const u16* __restrict__ U_all,
    float* __restrict__ Zb, float* __restrict__ Lb) {
    __shared__ u16 qA[64 * 72];
    __shared__ u16 QMb[64 * 72];
    __shared__ u16 Pb[64 * 72];
    const int tid = threadIdx.x;
    const int n = blockIdx.y;
    const int pi = blockIdx.x;
    int qt, tch;
    if (pi < 8)       { qt = 0; tch = pi; }
    else if (pi < 24) { qt = 1; tch = pi - 8; }
    else if (pi < 48) { qt = 2; tch = pi - 24; }
    else              { qt = 3; tch = pi - 48; }
    const int q0 = qt * 64, nP = qt + 1;

    const u16* k1g = fiveb + (0 * 8 + n) * 256 * 64;
    const u16* qg  = fiveb + (2 * 8 + n) * 256 * 64;
    const u16* v1g = v1T + n * 64 * 256;
    const u16* Mg = M_all + (size_t)(n * 256) * 4096;
    const u16* Ug = U_all + (size_t)(n * 256) * 4096;

    {   // stage qA
        int row = tid >> 2, cc = (tid & 3) * 16;
        const uint4* s = (const uint4*)(qg + (q0 + row) * 64 + cc);
        uint4 a = s[0], b = s[1];
        *(uint4*)&qA[row * 72 + cc] = a;
        *(uint4*)&qA[row * 72 + cc + 8] = b;
    }
    __syncthreads();

    const int w = tid >> 6, lane = tid & 63, quad = lane >> 4, l15 = lane & 15;
    const int r0 = w * 16;

    f32x4 Zc[4];
#pragma unroll
    for (int nt = 0; nt < 4; ++nt) Zc[nt] = (f32x4){0.f, 0.f, 0.f, 0.f};
    float lsum = 0.f;

    for (int tt = 0; tt < 8; ++tt) {
        const int t = tch * 8 + tt;
        const u16* Mt = Mg + (size_t)t * 4096;
        const u16* Ut = Ug + (size_t)t * 4096;

        // QM[q,k] = q . M_t^T   (B streamed from global)
        {
            bf16x8 a0 = *(const bf16x8*)&qA[(r0 + l15) * 72 + quad * 8];
            bf16x8 a1 = *(const bf16x8*)&qA[(r0 + l15) * 72 + 32 + quad * 8];
#pragma unroll
            for (int nt = 0; nt < 4; ++nt) {
                bf16x8 b0 = *(const bf16x8*)&Mt[(nt * 16 + l15) * 64 + quad * 8];
                bf16x8 b1 = *(const bf16x8*)&Mt[(nt * 16 + l15) * 64 + 32 + quad * 8];
                f32x4 c = {0.f, 0.f, 0.f, 0.f};
                c = MFMA(a0, b0, c, 0, 0, 0);
                c = MFMA(a1, b1, c, 0, 0, 0);
#pragma unroll
                for (int r = 0; r < 4; ++r)
                    QMb[(r0 + quad * 4 + r) * 72 + nt * 16 + l15] = f2bf(c[r]);
            }
        }
        bf16x8 qa0 = *(const bf16x8*)&QMb[(r0 + l15) * 72 + quad * 8];
        bf16x8 qa1 = *(const bf16x8*)&QMb[(r0 + l15) * 72 + 32 + quad * 8];

        f32x4 Gc[4];
#pragma unroll
        for (int nt = 0; nt < 4; ++nt) Gc[nt] = (f32x4){0.f, 0.f, 0.f, 0.f};

        for (int pt = 0; pt < nP; ++pt) {
            // S = QM . k1^T ; mask+exp -> Pb
#pragma unroll
            for (int nt = 0; nt < 4; ++nt) {
                bf16x8 b0 = *(const bf16x8*)&k1g[(pt * 64 + nt * 16 + l15) * 64 + quad * 8];
                bf16x8 b1 = *(const bf16x8*)&k1g[(pt * 64 + nt * 16 + l15) * 64 + 32 + quad * 8];
                f32x4 s = {0.f, 0.f, 0.f, 0.f};
                s = MFMA(qa0, b0, s, 0, 0, 0);
                s = MFMA(qa1, b1, s, 0, 0, 0);
                const int p = pt * 64 + nt * 16 + l15;
#pragma unroll
                for (int r = 0; r < 4; ++r) {
                    const int q = q0 + r0 + quad * 4 + r;
                    float wv = (p <= q && t <= q) ? __expf(s[r] * 0.015625f) : 0.f;
                    Pb[(r0 + quad * 4 + r) * 72 + nt * 16 + l15] = f2bf(wv);
                }
            }
            {   // L row partial sums
                const uint4* pr = (const uint4*)&Pb[(r0 + l15) * 72 + quad * 16];
                lsum += sum8(pr[0]) + sum8(pr[1]);
            }
            // G += P . v1tile  (B = v1T rows, p-contiguous, from global)
            bf16x8 pa0 = *(const bf16x8*)&Pb[(r0 + l15) * 72 + quad * 8];
            bf16x8 pa1 = *(const bf16x8*)&Pb[(r0 + l15) * 72 + 32 + quad * 8];
#pragma unroll
            for (int nt = 0; nt < 4; ++nt) {
                bf16x8 b0 = *(const bf16x8*)&v1g[(nt * 16 + l15) * 256 + pt * 64 + quad * 8];
                bf16x8 b1 = *(const bf16x8*)&v1g[(nt * 16 + l15) * 256 + pt * 64 + 32 + quad * 8];
                Gc[nt] = MFMA(pa0, b0, Gc[nt], 0, 0, 0);
                Gc[nt] = MFMA(pa1, b1, Gc[nt], 0, 0, 0);
            }
        }
        // Z += G . U_t  (G via wave-local LDS strip, reusing Pb)
#pragma unroll
        for (int nt = 0; nt < 4; ++nt)
#pragma unroll
            for (int r = 0; r < 4; ++r)
                Pb[(r0 + quad * 4 + r) * 72 + nt * 16 + l15] = f2bf(Gc[nt][r]);
        bf16x8 ga0 = *(const bf16x8*)&Pb[(r0 + l15) * 72 + quad * 8];
        bf16x8 ga1 = *(const bf16x8*)&Pb[(r0 + l15) * 72 + 32 + quad * 8];
#pragma unroll
        for (int nt = 0; nt < 4; ++nt) {
            bf16x8 b0 = *(const bf16x8*)&Ut[(nt * 16 + l15) * 64 + quad * 8];
            bf16x8 b1 = *(const bf16x8*)&Ut[(nt * 16 + l15) * 64 + 32 + quad * 8];
            Zc[nt] = MFMA(ga0, b0, Zc[nt], 0, 0, 0);
            Zc[nt] = MFMA(ga1, b1, Zc[nt], 0, 0, 0);
        }
    }

#pragma unroll
    for (int nt = 0; nt < 4; ++nt)
#pragma unroll
        for (int r = 0; r < 4; ++r) {
            const int q = q0 + r0 + quad * 4 + r;
            atomicAdd(Zb + ((size_t)n * 256 + q) * 64 + nt * 16 + l15, Zc[nt][r]);
        }
    lsum += __shfl_xor(lsum, 16);
    lsum += __shfl_xor(lsum, 32);
    if (quad == 0) atomicAdd(Lb + n * 256 + q0 + r0 + l15, lsum);
}

// ---------------- K5: zn[t][h*64+e] = bf16(Z/L)
__global__ __launch_bounds__(256) void zn_kernel(
    const float* __restrict__ Zb, const float* __restrict__ Lb, u16* __restrict__ zn) {
    const int flat = (blockIdx.x * 256 + threadIdx.x) * 4;
    const int t = flat >> 9, he = flat & 511, h = he >> 6, e = he & 63;
    const float L = Lb[h * 256 + t];
    const float4 z = *(const float4*)(Zb + ((size_t)h * 256 + t) * 64 + e);
    __attribute__((aligned(8))) u16 t4[4];
    t4[0] = f2bf(z.x / L); t4[1] = f2bf(z.y / L); t4[2] = f2bf(z.z / L); t4[3] = f2bf(z.w / L);
    *(uint2*)(zn + flat) = *(uint2*)t4;
}

// ---------------- K6: out = zn @ Wot^T + b_out (fp32 out), MFMA
__global__ __launch_bounds__(256) void out_mfma(
    const u16* __restrict__ zn, const u16* __restrict__ Wot,
    const float* __restrict__ b_out, float* __restrict__ out) {
    const int tid = threadIdx.x, w = tid >> 6, lane = tid & 63;
    const int quad = lane >> 4, l15 = lane & 15;
    const int m0 = blockIdx.x * 64 + w * 16;
    const int c0 = blockIdx.y * 64;
    f32x4 acc[4];
#pragma unroll
    for (int nt = 0; nt < 4; ++nt) acc[nt] = (f32x4){0.f, 0.f, 0.f, 0.f};
    for (int kc = 0; kc < 16; ++kc) {
        bf16x8 a = *(const bf16x8*)&zn[(size_t)(m0 + l15) * 512 + kc * 32 + quad * 8];
#pragma unroll
        for (int nt = 0; nt < 4; ++nt) {
            bf16x8 b = *(const bf16x8*)&Wot[(size_t)(c0 + nt * 16 + l15) * 512 + kc * 32 + quad * 8];
            acc[nt] = MFMA(a, b, acc[nt], 0, 0, 0);
        }
    }
#pragma unroll
    for (int nt = 0; nt < 4; ++nt) {
        const int col = c0 + nt * 16 + l15;
        const float b = b_out[col];
#pragma unroll
        for (int r = 0; r < 4; ++r)
            out[(size_t)(m0 + quad * 4 + r) * 512 + col] = acc[nt][r] + b;
    }
}

extern "C" void kernel_launch(void* const* d_in, const int* in_sizes, int n_in,
                              void* d_out, int out_size, void* d_ws, size_t ws_size,
                              hipStream_t stream) {
    const float* x       = (const float*)d_in[0];
    const float* W_kkqvv = (const float*)d_in[1];
    const float* b_kkqvv = (const float*)d_in[2];
    const float* W_Kq    = (const float*)d_in[3];
    const float* W_Vq    = (const float*)d_in[4];
    const float* W_out   = (const float*)d_in[5];
    const float* b_out   = (const float*)d_in[6];

    char* base = (char*)d_ws;
    u16*   fiveb = (u16*)base;                      // 1,310,720 B
    float* Zb    = (float*)(base + 1310720);        // 524,288 B
    float* Lb    = (float*)(base + 1835008);        // 8,192 B
    u16*   WKt   = (u16*)(base + 1843200);          // 4 MB
    u16*   WVt   = (u16*)(base + 6037504);          // 4 MB
    u16*   M_all = (u16*)(base + 10231808);         // 16 MB
    u16*   U_all = (u16*)(base + 27009024);         // 16 MB
    // aliased into M_all's region (dead after proj; M_all written later):
    u16*   Wt    = (u16*)(base + 10231808);         // 2,621,440 B
    u16*   xb    = (u16*)(base + 12853248);         // 262,144 B
    u16*   Wot   = (u16*)(base + 43786240);         // 524,288 B
    u16*   v1T   = (u16*)(base + 44310528);         // 262,144 B
    u16*   zn    = (u16*)(base + 44572672);         // 262,144 B  (end ~42.8 MB)

    hipMemsetAsync(Zb, 0, (HH * TT * DHH + HH * TT) * sizeof(float), stream);
    prep_kernel<<<392, 256, 0, stream>>>(W_kkqvv, W_out, x, Wt, Wot, xb);
    proj_mfma<<<dim3(4, 40), 256, 0, stream>>>(xb, Wt, b_kkqvv, fiveb, v1T);
    transpose_w<<<dim3(64, 8, 2), 256, 0, stream>>>(W_Kq, W_Vq, WKt, WVt);
    mu_gemm<<<dim3(64, 8, 2), 256, 0, stream>>>(fiveb, WKt, WVt, M_all, U_all);
    main_kernel<<<dim3(80, 8), 256, 0, stream>>>(fiveb, v1T, M_all, U_all, Zb, Lb);
    zn_kernel<<<128, 256, 0, stream>>>(Zb, Lb, zn);
    out_mfma<<<dim3(4, 8), 256, 0, stream>>>(zn, Wot, b_out, (float*)d_out);
}